// Round 10
// baseline (326.444 us; speedup 1.0000x reference)
//
#include <hip/hip_runtime.h>
#include <hip/hip_bf16.h>
#include <hip/hip_fp16.h>

#define N_NODES 100000
#define N_EDGES 1600000
#define IN_DIM 256
#define HIDDEN 128
#define NCLS 40
#define NCLS_PAD 48      // padded to 3 MFMA n-tiles

#define N_BUCKETS 256
#define NPB 391          // nodes per bucket = ceil(100000/256)
#define BCAP 8192        // bucket capacity (mean 6256, +24 sigma)
#define EPT 16           // edges per thread in bin phase
#define BIN_WG 4096      // edges per workgroup (256*16)
#define BIN_BLOCKS 391   // ceil(N_EDGES / BIN_WG)
#define GEMM1_BLOCKS 782 // ceil(N_NODES / 128)

typedef __attribute__((ext_vector_type(8))) _Float16 half8;
typedef __attribute__((ext_vector_type(4))) _Float16 half4f;
typedef __attribute__((ext_vector_type(4))) float floatx4;

// ---------------- k_prep: W1T / W2T fp16 transposes + bfill zero ----------------

__global__ __launch_bounds__(256) void k_prep(const float* __restrict__ W1, __half* __restrict__ W1T,
                                              const float* __restrict__ W2, __half* __restrict__ W2T,
                                              int* __restrict__ bfill) {
    const int t = threadIdx.x;
    if (blockIdx.x < 128) {              // W1T: [n][k] fp16, 128 x 256
        int i = blockIdx.x * 256 + t;
        int k = i >> 7, n = i & 127;
        W1T[n * IN_DIM + k] = __float2half_rn(W1[i]);
    } else if (blockIdx.x == 128) {      // W2T: [n][k] fp16, 48 x 128, zero-pad n>=40
        for (int i = t; i < NCLS_PAD * HIDDEN; i += 256) {
            int n = i >> 7, k = i & 127;
            W2T[n * HIDDEN + k] = (n < NCLS) ? __float2half_rn(W2[k * NCLS + n]) : __float2half_rn(0.f);
        }
    } else {
        bfill[t] = 0;
    }
}

// ---------------- k_binmm: bin/gemm blocks INTERLEAVED mod 3 (1173 = 3*391) ----------------
// b%3==0 -> bin (391 blocks), else gemm (782 blocks). Bin phase: round-3 proven config.
// GEMM phase: B staged in LDS per k-half; A direct per-lane from X with DEPTH-3
// register prefetch (4 rotating buffers, compile-time indices): ~930cy of MFMA work
// per wave now covers the ~900cy HBM latency. VGPR ~112 -> still 4 waves/SIMD;
// LDS cap (4 blocks/CU) unchanged.

__global__ __launch_bounds__(256) void k_binmm(const int* __restrict__ src, const int* __restrict__ dst,
                                               int* __restrict__ bfill,
                                               unsigned long long* __restrict__ bpair,
                                               const float* __restrict__ X,
                                               const __half* __restrict__ W1T,
                                               __half* __restrict__ H1s) {
    __shared__ __align__(16) char smraw[39936];   // union: bin(39936) / gemm1 Bsm(34816)
    const int t = threadIdx.x;
    const int blk = blockIdx.x;

    if (blk % 3 == 0) {
        // ---- bin phase (bin_id = blk/3 in [0,391)) ----
        const int bin_id = blk / 3;
        int* hist   = (int*)smraw;                               // 256
        int* bstart = hist + 256;                                // 256
        int* gbase  = bstart + 256;                              // 256
        unsigned long long* stage = (unsigned long long*)(smraw + 3072);   // 4096 (32 KB)
        unsigned char* bid = (unsigned char*)(smraw + 3072 + 32768);       // 4096
        hist[t] = 0;
        __syncthreads();
        const long e0 = (long)bin_id * BIN_WG;
        const int n_valid = (int)min((long)BIN_WG, (long)N_EDGES - e0);
        int msrc[EPT], mdst[EPT], moff[EPT];
        #pragma unroll
        for (int i = 0; i < EPT; i++) {
            long e = e0 + t + i * 256;
            if (e < N_EDGES) {
                msrc[i] = src[e];
                mdst[i] = dst[e];
                moff[i] = atomicAdd(&hist[mdst[i] / NPB], 1);
            } else {
                mdst[i] = -1;
            }
        }
        __syncthreads();
        if (t < 64) {   // wave 0: exclusive scan of hist[256]
            int carry = 0;
            #pragma unroll
            for (int c = 0; c < 4; c++) {
                int idx = c * 64 + t;
                int hv = hist[idx];
                int s = hv;
                #pragma unroll
                for (int d2 = 1; d2 < 64; d2 <<= 1) {
                    int u = __shfl_up(s, d2, 64);
                    if (t >= d2) s += u;
                }
                bstart[idx] = carry + (s - hv);
                carry += __shfl(s, 63, 64);
            }
        }
        __syncthreads();
        int h = hist[t];
        gbase[t] = (h > 0) ? atomicAdd(&bfill[t], h) : 0;
        #pragma unroll
        for (int i = 0; i < EPT; i++) {
            if (mdst[i] >= 0) {
                int b = mdst[i] / NPB;
                int pos = bstart[b] + moff[i];
                stage[pos] = ((unsigned long long)(unsigned)mdst[i] << 32) | (unsigned)msrc[i];
                bid[pos] = (unsigned char)b;
            }
        }
        __syncthreads();
        for (int i = t; i < n_valid; i += 256) {
            int b = bid[i];
            int dest = gbase[b] + (i - bstart[b]);
            bpair[(long)b * BCAP + dest] = stage[i];
        }
        return;
    }

    // ---- gemm1 phase (gemm_id = blk - blk/3 - 1 in [0,782)) ----
    _Float16 (*Bsm)[136] = (_Float16(*)[136])smraw;   // 128 x 136 fp16 (+8 pad: +4 banks/row)
    const int gemm_id = blk - blk / 3 - 1;
    const int wave = t >> 6;
    const int lane = t & 63;
    const int m16  = lane & 15;
    const int kq   = lane >> 4;
    const int row0 = gemm_id * 128;
    const int arow0 = row0 + wave * 32 + m16;
    const int arow1 = arow0 + 16;
    const bool va0 = arow0 < N_NODES;
    const bool va1 = arow1 < N_NODES;
    const float* pX0 = X + (long)arow0 * IN_DIM + kq * 8;
    const float* pX1 = X + (long)arow1 * IN_DIM + kq * 8;
    const float4 z4 = make_float4(0.f, 0.f, 0.f, 0.f);

    floatx4 acc[2][8];
    #pragma unroll
    for (int mt = 0; mt < 2; mt++)
        #pragma unroll
        for (int i = 0; i < 8; i++) acc[mt][i] = (floatx4)0.f;

    float4 A[4][2][2];   // 4 rotating depth-3 prefetch buffers (64 VGPR)
    auto loadA4 = [&](int buf, int kbase) {
        if (va0) { A[buf][0][0] = *(const float4*)(pX0 + kbase); A[buf][0][1] = *(const float4*)(pX0 + kbase + 4); }
        else     { A[buf][0][0] = z4; A[buf][0][1] = z4; }
        if (va1) { A[buf][1][0] = *(const float4*)(pX1 + kbase); A[buf][1][1] = *(const float4*)(pX1 + kbase + 4); }
        else     { A[buf][1][0] = z4; A[buf][1][1] = z4; }
    };

    loadA4(0, 0);        // prologue: steps 0..2 in flight before B staging
    loadA4(1, 32);
    loadA4(2, 64);

    #pragma unroll
    for (int h = 0; h < 2; h++) {        // two k-halves of 128
        // stage B half h: W1T[n][h*128 .. +128) -> Bsm[n][0..128)
        #pragma unroll
        for (int i = 0; i < 8; i++) {
            int c = t + i * 256;         // 2048 half8-chunks
            int n = c >> 4, k8 = c & 15;
            *(half8*)&Bsm[n][k8 * 8] = *(const half8*)&W1T[n * IN_DIM + h * 128 + k8 * 8];
        }
        __syncthreads();
        #pragma unroll
        for (int s4 = 0; s4 < 4; s4++) { // 4 k-steps of 32 per half
            const int s = h * 4 + s4;    // global step 0..7 (compile-time)
            if (s + 3 < 8) loadA4((s + 3) % 4, (s + 3) * 32);   // depth-3 prefetch
            const float4 (*cA)[2] = A[s % 4];
            half8 a0, a1;
            a0[0] = (_Float16)cA[0][0].x; a0[1] = (_Float16)cA[0][0].y;
            a0[2] = (_Float16)cA[0][0].z; a0[3] = (_Float16)cA[0][0].w;
            a0[4] = (_Float16)cA[0][1].x; a0[5] = (_Float16)cA[0][1].y;
            a0[6] = (_Float16)cA[0][1].z; a0[7] = (_Float16)cA[0][1].w;
            a1[0] = (_Float16)cA[1][0].x; a1[1] = (_Float16)cA[1][0].y;
            a1[2] = (_Float16)cA[1][0].z; a1[3] = (_Float16)cA[1][0].w;
            a1[4] = (_Float16)cA[1][1].x; a1[5] = (_Float16)cA[1][1].y;
            a1[6] = (_Float16)cA[1][1].z; a1[7] = (_Float16)cA[1][1].w;
            const _Float16* bbase = &Bsm[m16][s4 * 32 + kq * 8];
            #pragma unroll
            for (int nt = 0; nt < 8; nt++) {
                half8 b = *(const half8*)(bbase + nt * 16 * 136);
                acc[0][nt] = __builtin_amdgcn_mfma_f32_16x16x32_f16(a0, b, acc[0][nt], 0, 0, 0);
                acc[1][nt] = __builtin_amdgcn_mfma_f32_16x16x32_f16(a1, b, acc[1][nt], 0, 0, 0);
            }
        }
        if (h == 0) __syncthreads();     // all waves done reading Bsm before restage
    }

    #pragma unroll
    for (int mt = 0; mt < 2; mt++) {
        const int gr0 = row0 + wave * 32 + mt * 16 + kq * 4;
        #pragma unroll
        for (int nt = 0; nt < 8; nt++) {
            int c = nt * 16 + m16;
            #pragma unroll
            for (int r = 0; r < 4; r++) {
                if (gr0 + r < N_NODES)
                    H1s[(long)(gr0 + r) * HIDDEN + c] = __float2half_rn(acc[mt][nt][r]);
            }
        }
    }
}

// ---------------- k_build: histogram -> prefix -> row_ptr/dinv -> scatter ----------------
// 512 threads/block (8 waves/CU): TLP for the atomic/gather loops.

__global__ __launch_bounds__(512) void k_build(const int* __restrict__ bfill,
                                               const unsigned long long* __restrict__ bpair,
                                               int* __restrict__ row_ptr, float* __restrict__ dinv,
                                               int* __restrict__ col) {
    __shared__ int h[NPB];
    __shared__ int pfx[NPB];
    __shared__ int sred[8];
    const int b  = blockIdx.x;
    const int nb = b * NPB;
    const int nn = min(NPB, N_NODES - nb);
    const int t  = threadIdx.x;
    int v = (t < b) ? bfill[t] : 0;      // t in [0,512); bfill has 256 entries, b<=255 guards
    #pragma unroll
    for (int dl = 32; dl > 0; dl >>= 1) v += __shfl_down(v, dl, 64);
    if ((t & 63) == 0) sred[t >> 6] = v;
    for (int i = t; i < NPB; i += 512) h[i] = 0;
    __syncthreads();
    int base_b = 0;
    #pragma unroll
    for (int i = 0; i < 8; i++) base_b += sred[i];
    const int n = bfill[b];
    for (int i = t; i < n; i += 512) {
        int dd = (int)(bpair[(long)b * BCAP + i] >> 32);
        atomicAdd(&h[dd - nb], 1);
    }
    __syncthreads();
    if (t < 64) {   // wave 0: exclusive scan of degrees
        int carry = 0;
        #pragma unroll
        for (int c = 0; c < (NPB + 63) / 64; c++) {
            int idx = c * 64 + t;
            int hv = (idx < nn) ? h[idx] : 0;
            int s = hv;
            #pragma unroll
            for (int d2 = 1; d2 < 64; d2 <<= 1) {
                int u = __shfl_up(s, d2, 64);
                if (t >= d2) s += u;
            }
            if (idx < nn) {
                int ex = base_b + carry + (s - hv);
                pfx[idx] = ex;
                row_ptr[nb + idx] = ex;
                dinv[nb + idx] = rsqrtf((float)(hv + 1));   // +1 self-loop
            }
            carry += __shfl(s, 63, 64);
        }
    }
    __syncthreads();
    for (int i = t; i < nn; i += 512) h[i] = 0;   // reuse as fill counters
    __syncthreads();
    for (int i = t; i < n; i += 512) {
        unsigned long long p = bpair[(long)b * BCAP + i];
        int dd = (int)(p >> 32);
        int ss = (int)(p & 0xFFFFFFFFu);
        int pos = pfx[dd - nb] + atomicAdd(&h[dd - nb], 1);
        col[pos] = ss;
    }
    if (b == 0 && t == 0) row_ptr[N_NODES] = N_EDGES;
}

// ---------------- k_agg1g2: Agg1 (+bias+ReLU, pre-scale) + MFMA GEMM2 -> H2s fp16 ----------------
// Block = 16 nodes, each wave serially aggregates 4 nodes with a full-row gather per
// edge (64 lanes x half2 = 256B). e0/e1 forced to SGPR via readfirstlane so col[e..]
// are SGPR scalar loads; dinv[col[e]] are uniform-address scalar loads (SMEM pipe)
// and the sym-norm scale folds into the accumulate. Main loop unroll 16 (avg degree
// is 16: most rows now take ONE latency round trip instead of two).

__global__ __launch_bounds__(256) void k_agg1g2(const __half* __restrict__ H1s,
                                                const int* __restrict__ row_ptr,
                                                const int* __restrict__ col,
                                                const float* __restrict__ dinv,
                                                const float* __restrict__ b1,
                                                const __half* __restrict__ W2T,
                                                __half* __restrict__ H2s) {
    __shared__ __align__(16) _Float16 rows[16][136];   // +8 pad: 16B-aligned, 2-way-max banks
    const int wave = threadIdx.x >> 6;
    const int lane = threadIdx.x & 63;
    const __half2* base = (const __half2*)H1s;   // row stride 64 half2
    const float2 bb = ((const float2*)b1)[lane];
    const int d00 = blockIdx.x * 16 + wave * 4;

    #pragma unroll
    for (int i = 0; i < 4; i++) {
        const int d = d00 + i;
        const int e0 = __builtin_amdgcn_readfirstlane(row_ptr[d]);
        const int e1 = __builtin_amdgcn_readfirstlane(row_ptr[d + 1]);
        const float dd = dinv[d];
        float ax = 0.f, ay = 0.f;
        int e = e0;
        for (; e + 15 < e1; e += 16) {    // 16 gathers in flight
            int sc[16];
            float dv[16];
            float2 fv[16];
            #pragma unroll
            for (int u = 0; u < 16; u++) sc[u] = col[e + u];
            #pragma unroll
            for (int u = 0; u < 16; u++) dv[u] = dinv[sc[u]];
            #pragma unroll
            for (int u = 0; u < 16; u++) fv[u] = __half22float2(base[(long)sc[u] * 64 + lane]);
            #pragma unroll
            for (int u = 0; u < 16; u++) { ax += dv[u] * fv[u].x; ay += dv[u] * fv[u].y; }
        }
        for (; e + 7 < e1; e += 8) {
            int sc[8];
            float dv[8];
            float2 fv[8];
            #pragma unroll
            for (int u = 0; u < 8; u++) sc[u] = col[e + u];
            #pragma unroll
            for (int u = 0; u < 8; u++) dv[u] = dinv[sc[u]];
            #pragma unroll
            for (int u = 0; u < 8; u++) fv[u] = __half22float2(base[(long)sc[u] * 64 + lane]);
            #pragma unroll
            for (int u = 0; u < 8; u++) { ax += dv[u] * fv[u].x; ay += dv[u] * fv[u].y; }
        }
        for (; e + 3 < e1; e += 4) {
            int s0 = col[e], s1 = col[e + 1], s2 = col[e + 2], s3 = col[e + 3];
            float d0 = dinv[s0], d1 = dinv[s1], d2 = dinv[s2], d3 = dinv[s3];
            float2 f0 = __half22float2(base[(long)s0 * 64 + lane]);
            float2 f1 = __half22float2(base[(long)s1 * 64 + lane]);
            float2 f2 = __half22float2(base[(long)s2 * 64 + lane]);
            float2 f3 = __half22float2(base[(long)s3 * 64 + lane]);
            ax += d0 * f0.x + d1 * f1.x + d2 * f2.x + d3 * f3.x;
            ay += d0 * f0.y + d1 * f1.y + d2 * f2.y + d3 * f3.y;
        }
        for (; e < e1; e++) {
            int s = col[e];
            float dv = dinv[s];
            float2 f = __half22float2(base[(long)s * 64 + lane]);
            ax += dv * f.x; ay += dv * f.y;
        }
        // self-loop (unscaled H1 row x dd)
        float2 fs = __half22float2(base[(long)d * 64 + lane]);
        ax += dd * fs.x; ay += dd * fs.y;
        // bias + relu, then pre-scale by dd so the layer-2 MFMA needs no post-scale
        float ox = fmaxf(dd * ax + bb.x, 0.f) * dd;
        float oy = fmaxf(dd * ay + bb.y, 0.f) * dd;
        *(__half2*)&rows[wave * 4 + i][lane * 2] =
            __halves2half2(__float2half_rn(ox), __float2half_rn(oy));
    }
    __syncthreads();

    if (wave < 3) {   // 3 n-tiles of 16 cols (48 padded, 40 real)
        const int m16 = lane & 15;
        const int kq  = lane >> 4;
        floatx4 acc = (floatx4)0.f;
        #pragma unroll
        for (int ks = 0; ks < 4; ks++) {
            half8 a = *(const half8*)&rows[m16][ks * 32 + kq * 8];
            half8 b = *(const half8*)&W2T[(wave * 16 + m16) * HIDDEN + ks * 32 + kq * 8];
            acc = __builtin_amdgcn_mfma_f32_16x16x32_f16(a, b, acc, 0, 0, 0);
        }
        const int c = wave * 16 + m16;
        if (c < NCLS) {
            const int gr0 = blockIdx.x * 16 + kq * 4;
            #pragma unroll
            for (int r = 0; r < 4; r++)
                H2s[(long)(gr0 + r) * NCLS + c] = __float2half_rn(acc[r]);
        }
    }
}

// ---------------- Aggregation 2 (+bias) -> fp32 out. 12 nodes x 5 half8-lanes per wave ----------------

__global__ __launch_bounds__(256) void k_agg2(const __half* __restrict__ H2s,
                                              const int* __restrict__ row_ptr,
                                              const int* __restrict__ col,
                                              const float* __restrict__ dinv,
                                              const float* __restrict__ b2,
                                              float* __restrict__ out) {
    const int wave = threadIdx.x >> 6;
    const int lane = threadIdx.x & 63;
    const int g = lane / 5;               // 0..11 active, lanes 60-63 idle
    const int f = lane - g * 5;           // 0..4 -> feats 8f..8f+7
    const int d = blockIdx.x * 48 + wave * 12 + g;
    const bool act = (g < 12) && (d < N_NODES);
    int e0 = 0, e1 = 0;
    if (act) { e0 = row_ptr[d]; e1 = row_ptr[d + 1]; }
    const half8* base8 = (const half8*)H2s;   // row stride 5 half8
    float s0 = 0.f, s1 = 0.f, s2 = 0.f, s3 = 0.f, s4 = 0.f, s5 = 0.f, s6 = 0.f, s7 = 0.f;
    int e = e0;
    while (__any(e < e1)) {
        #pragma unroll
        for (int u = 0; u < 8; u++) {     // 8 gathers in flight per group
            if (e + u < e1) {
                half8 v = base8[(long)col[e + u] * 5 + f];
                s0 += (float)v[0]; s1 += (float)v[1]; s2 += (float)v[2]; s3 += (float)v[3];
                s4 += (float)v[4]; s5 += (float)v[5]; s6 += (float)v[6]; s7 += (float)v[7];
            }
        }
        e += 8;
    }
    if (act) {
        half8 v = base8[(long)d * 5 + f];   // self-loop (pre-scaled)
        s0 += (float)v[0]; s1 += (float)v[1]; s2 += (float)v[2]; s3 += (float)v[3];
        s4 += (float)v[4]; s5 += (float)v[5]; s6 += (float)v[6]; s7 += (float)v[7];
        float dd = dinv[d];
        float4 bb0 = ((const float4*)b2)[f * 2];
        float4 bb1 = ((const float4*)b2)[f * 2 + 1];
        float4 o0 = make_float4(dd * s0 + bb0.x, dd * s1 + bb0.y, dd * s2 + bb0.z, dd * s3 + bb0.w);
        float4 o1 = make_float4(dd * s4 + bb1.x, dd * s5 + bb1.y, dd * s6 + bb1.z, dd * s7 + bb1.w);
        ((float4*)out)[(long)d * 10 + f * 2]     = o0;
        ((float4*)out)[(long)d * 10 + f * 2 + 1] = o1;
    }
}

// ---------------- launch ----------------

extern "C" void kernel_launch(void* const* d_in, const int* in_sizes, int n_in,
                              void* d_out, int out_size, void* d_ws, size_t ws_size,
                              hipStream_t stream) {
    const float* x  = (const float*)d_in[0];
    const int*   ei = (const int*)d_in[1];
    const float* W1 = (const float*)d_in[2];
    const float* b1 = (const float*)d_in[3];
    const float* W2 = (const float*)d_in[4];
    const float* b2 = (const float*)d_in[5];
    const int* srcE = ei;
    const int* dstE = ei + N_EDGES;

    int*   row_ptr = (int*)d_ws;                    // 100032 ints
    int*   bfill   = row_ptr + 100032;              // 256
    int*   col     = bfill + 256;                   // 1600000
    float* dinv    = (float*)(col + N_EDGES);       // 100032 floats
    __half* H1s    = (__half*)(dinv + 100032);      // 12.8M halfs (25.6 MB)
    __half* H2s    = H1s + (long)N_NODES * HIDDEN;  // 4M halfs (8 MB)
    __half* W1T    = H2s + (long)N_NODES * NCLS;    // 32768 halfs
    __half* W2T    = W1T + IN_DIM * HIDDEN;         // 6144 halfs
    unsigned long long* bpair = (unsigned long long*)(W2T + NCLS_PAD * HIDDEN);  // 2.1M (16.8 MB)

    k_prep   <<<130, 256, 0, stream>>>(W1, W1T, W2, W2T, bfill);
    k_binmm  <<<BIN_BLOCKS + GEMM1_BLOCKS, 256, 0, stream>>>(srcE, dstE, bfill, bpair, x, W1T, H1s);
    k_build  <<<N_BUCKETS, 512, 0, stream>>>(bfill, bpair, row_ptr, dinv, col);
    k_agg1g2 <<<N_NODES / 16, 256, 0, stream>>>(H1s, row_ptr, col, dinv, b1, W2T, H2s);
    k_agg2   <<<(N_NODES + 47) / 48, 256, 0, stream>>>(H2s, row_ptr, col, dinv, b2, (float*)d_out);
}

// Round 11
// 323.780 us; speedup vs baseline: 1.0082x; 1.0082x over previous
//
#include <hip/hip_runtime.h>
#include <hip/hip_bf16.h>
#include <hip/hip_fp16.h>

#define N_NODES 100000
#define N_EDGES 1600000
#define IN_DIM 256
#define HIDDEN 128
#define NCLS 40
#define NCLS_PAD 48      // padded to 3 MFMA n-tiles

#define N_BUCKETS 256
#define NPB 391          // nodes per bucket = ceil(100000/256)
#define BCAP 8192        // bucket capacity (mean 6256, +24 sigma)
#define EPT 16           // edges per thread in bin phase
#define BIN_WG 4096      // edges per workgroup (256*16)
#define BIN_BLOCKS 391   // ceil(N_EDGES / BIN_WG)
#define GEMM1_BLOCKS 782 // ceil(N_NODES / 128)

typedef __attribute__((ext_vector_type(8))) _Float16 half8;
typedef __attribute__((ext_vector_type(4))) _Float16 half4f;
typedef __attribute__((ext_vector_type(4))) float floatx4;

// ---------------- k_prep: W1T / W2T fp16 transposes + bfill zero ----------------

__global__ __launch_bounds__(256) void k_prep(const float* __restrict__ W1, __half* __restrict__ W1T,
                                              const float* __restrict__ W2, __half* __restrict__ W2T,
                                              int* __restrict__ bfill) {
    const int t = threadIdx.x;
    if (blockIdx.x < 128) {              // W1T: [n][k] fp16, 128 x 256
        int i = blockIdx.x * 256 + t;
        int k = i >> 7, n = i & 127;
        W1T[n * IN_DIM + k] = __float2half_rn(W1[i]);
    } else if (blockIdx.x == 128) {      // W2T: [n][k] fp16, 48 x 128, zero-pad n>=40
        for (int i = t; i < NCLS_PAD * HIDDEN; i += 256) {
            int n = i >> 7, k = i & 127;
            W2T[n * HIDDEN + k] = (n < NCLS) ? __float2half_rn(W2[k * NCLS + n]) : __float2half_rn(0.f);
        }
    } else {
        bfill[t] = 0;
    }
}

// ---------------- k_binmm: bin/gemm blocks INTERLEAVED mod 3 (1173 = 3*391) ----------------
// b%3==0 -> bin (391 blocks), else gemm (782 blocks). Bin phase: round-3 proven config.
// GEMM phase: B staged in LDS per k-half; A direct per-lane from X with DEPTH-2
// register prefetch (3 rotating buffers, compile-time indices). Depth-3 measured
// null-to-negative (round 10): gemm latency-hiding is saturated at depth-2.

__global__ __launch_bounds__(256) void k_binmm(const int* __restrict__ src, const int* __restrict__ dst,
                                               int* __restrict__ bfill,
                                               unsigned long long* __restrict__ bpair,
                                               const float* __restrict__ X,
                                               const __half* __restrict__ W1T,
                                               __half* __restrict__ H1s) {
    __shared__ __align__(16) char smraw[39936];   // union: bin(39936) / gemm1 Bsm(34816)
    const int t = threadIdx.x;
    const int blk = blockIdx.x;

    if (blk % 3 == 0) {
        // ---- bin phase (bin_id = blk/3 in [0,391)) ----
        const int bin_id = blk / 3;
        int* hist   = (int*)smraw;                               // 256
        int* bstart = hist + 256;                                // 256
        int* gbase  = bstart + 256;                              // 256
        unsigned long long* stage = (unsigned long long*)(smraw + 3072);   // 4096 (32 KB)
        unsigned char* bid = (unsigned char*)(smraw + 3072 + 32768);       // 4096
        hist[t] = 0;
        __syncthreads();
        const long e0 = (long)bin_id * BIN_WG;
        const int n_valid = (int)min((long)BIN_WG, (long)N_EDGES - e0);
        int msrc[EPT], mdst[EPT], moff[EPT];
        #pragma unroll
        for (int i = 0; i < EPT; i++) {
            long e = e0 + t + i * 256;
            if (e < N_EDGES) {
                msrc[i] = src[e];
                mdst[i] = dst[e];
                moff[i] = atomicAdd(&hist[mdst[i] / NPB], 1);
            } else {
                mdst[i] = -1;
            }
        }
        __syncthreads();
        if (t < 64) {   // wave 0: exclusive scan of hist[256]
            int carry = 0;
            #pragma unroll
            for (int c = 0; c < 4; c++) {
                int idx = c * 64 + t;
                int hv = hist[idx];
                int s = hv;
                #pragma unroll
                for (int d2 = 1; d2 < 64; d2 <<= 1) {
                    int u = __shfl_up(s, d2, 64);
                    if (t >= d2) s += u;
                }
                bstart[idx] = carry + (s - hv);
                carry += __shfl(s, 63, 64);
            }
        }
        __syncthreads();
        int h = hist[t];
        gbase[t] = (h > 0) ? atomicAdd(&bfill[t], h) : 0;
        #pragma unroll
        for (int i = 0; i < EPT; i++) {
            if (mdst[i] >= 0) {
                int b = mdst[i] / NPB;
                int pos = bstart[b] + moff[i];
                stage[pos] = ((unsigned long long)(unsigned)mdst[i] << 32) | (unsigned)msrc[i];
                bid[pos] = (unsigned char)b;
            }
        }
        __syncthreads();
        for (int i = t; i < n_valid; i += 256) {
            int b = bid[i];
            int dest = gbase[b] + (i - bstart[b]);
            bpair[(long)b * BCAP + dest] = stage[i];
        }
        return;
    }

    // ---- gemm1 phase (gemm_id = blk - blk/3 - 1 in [0,782)) ----
    _Float16 (*Bsm)[136] = (_Float16(*)[136])smraw;   // 128 x 136 fp16 (+8 pad: +4 banks/row)
    const int gemm_id = blk - blk / 3 - 1;
    const int wave = t >> 6;
    const int lane = t & 63;
    const int m16  = lane & 15;
    const int kq   = lane >> 4;
    const int row0 = gemm_id * 128;
    const int arow0 = row0 + wave * 32 + m16;
    const int arow1 = arow0 + 16;
    const bool va0 = arow0 < N_NODES;
    const bool va1 = arow1 < N_NODES;
    const float* pX0 = X + (long)arow0 * IN_DIM + kq * 8;
    const float* pX1 = X + (long)arow1 * IN_DIM + kq * 8;
    const float4 z4 = make_float4(0.f, 0.f, 0.f, 0.f);

    floatx4 acc[2][8];
    #pragma unroll
    for (int mt = 0; mt < 2; mt++)
        #pragma unroll
        for (int i = 0; i < 8; i++) acc[mt][i] = (floatx4)0.f;

    float4 A[3][2][2];   // 3 rotating depth-2 prefetch buffers
    auto loadA3 = [&](int buf, int kbase) {
        if (va0) { A[buf][0][0] = *(const float4*)(pX0 + kbase); A[buf][0][1] = *(const float4*)(pX0 + kbase + 4); }
        else     { A[buf][0][0] = z4; A[buf][0][1] = z4; }
        if (va1) { A[buf][1][0] = *(const float4*)(pX1 + kbase); A[buf][1][1] = *(const float4*)(pX1 + kbase + 4); }
        else     { A[buf][1][0] = z4; A[buf][1][1] = z4; }
    };

    loadA3(0, 0);        // prologue: steps 0 and 1 in flight before B staging
    loadA3(1, 32);

    #pragma unroll
    for (int h = 0; h < 2; h++) {        // two k-halves of 128
        // stage B half h: W1T[n][h*128 .. +128) -> Bsm[n][0..128)
        #pragma unroll
        for (int i = 0; i < 8; i++) {
            int c = t + i * 256;         // 2048 half8-chunks
            int n = c >> 4, k8 = c & 15;
            *(half8*)&Bsm[n][k8 * 8] = *(const half8*)&W1T[n * IN_DIM + h * 128 + k8 * 8];
        }
        __syncthreads();
        #pragma unroll
        for (int s4 = 0; s4 < 4; s4++) { // 4 k-steps of 32 per half
            const int s = h * 4 + s4;    // global step 0..7 (compile-time)
            if (s + 2 < 8) loadA3((s + 2) % 3, (s + 2) * 32);   // depth-2 prefetch
            const float4 (*cA)[2] = A[s % 3];
            half8 a0, a1;
            a0[0] = (_Float16)cA[0][0].x; a0[1] = (_Float16)cA[0][0].y;
            a0[2] = (_Float16)cA[0][0].z; a0[3] = (_Float16)cA[0][0].w;
            a0[4] = (_Float16)cA[0][1].x; a0[5] = (_Float16)cA[0][1].y;
            a0[6] = (_Float16)cA[0][1].z; a0[7] = (_Float16)cA[0][1].w;
            a1[0] = (_Float16)cA[1][0].x; a1[1] = (_Float16)cA[1][0].y;
            a1[2] = (_Float16)cA[1][0].z; a1[3] = (_Float16)cA[1][0].w;
            a1[4] = (_Float16)cA[1][1].x; a1[5] = (_Float16)cA[1][1].y;
            a1[6] = (_Float16)cA[1][1].z; a1[7] = (_Float16)cA[1][1].w;
            const _Float16* bbase = &Bsm[m16][s4 * 32 + kq * 8];
            #pragma unroll
            for (int nt = 0; nt < 8; nt++) {
                half8 b = *(const half8*)(bbase + nt * 16 * 136);
                acc[0][nt] = __builtin_amdgcn_mfma_f32_16x16x32_f16(a0, b, acc[0][nt], 0, 0, 0);
                acc[1][nt] = __builtin_amdgcn_mfma_f32_16x16x32_f16(a1, b, acc[1][nt], 0, 0, 0);
            }
        }
        if (h == 0) __syncthreads();     // all waves done reading Bsm before restage
    }

    #pragma unroll
    for (int mt = 0; mt < 2; mt++) {
        const int gr0 = row0 + wave * 32 + mt * 16 + kq * 4;
        #pragma unroll
        for (int nt = 0; nt < 8; nt++) {
            int c = nt * 16 + m16;
            #pragma unroll
            for (int r = 0; r < 4; r++) {
                if (gr0 + r < N_NODES)
                    H1s[(long)(gr0 + r) * HIDDEN + c] = __float2half_rn(acc[mt][nt][r]);
            }
        }
    }
}

// ---------------- k_build: SINGLE-PASS bucket build ----------------
// Bucket staged into LDS on the one global read (ushort local-dst + int src = 48KB);
// histogram, scan, and scatter then run entirely from LDS — the old second global
// sweep of bpair (50KB/block, global latency at 1 block/CU) is gone. 512 threads.

__global__ __launch_bounds__(512) void k_build(const int* __restrict__ bfill,
                                               const unsigned long long* __restrict__ bpair,
                                               int* __restrict__ row_ptr, float* __restrict__ dinv,
                                               int* __restrict__ col) {
    __shared__ unsigned short ldst[BCAP];   // 16 KB: dst - nb (NPB=391 fits ushort)
    __shared__ int lsrc[BCAP];              // 32 KB
    __shared__ int h[NPB];
    __shared__ int pfx[NPB];
    __shared__ int sred[8];
    const int b  = blockIdx.x;
    const int nb = b * NPB;
    const int nn = min(NPB, N_NODES - nb);
    const int t  = threadIdx.x;
    int v = (t < b) ? bfill[t] : 0;      // t in [0,512); bfill has 256 entries, b<=255 guards
    #pragma unroll
    for (int dl = 32; dl > 0; dl >>= 1) v += __shfl_down(v, dl, 64);
    if ((t & 63) == 0) sred[t >> 6] = v;
    for (int i = t; i < NPB; i += 512) h[i] = 0;
    __syncthreads();
    int base_b = 0;
    #pragma unroll
    for (int i = 0; i < 8; i++) base_b += sred[i];
    const int n = bfill[b];
    for (int i = t; i < n; i += 512) {   // the ONLY global read of this bucket
        unsigned long long p = bpair[(long)b * BCAP + i];
        int dl = (int)(p >> 32) - nb;
        ldst[i] = (unsigned short)dl;
        lsrc[i] = (int)(p & 0xFFFFFFFFu);
        atomicAdd(&h[dl], 1);
    }
    __syncthreads();
    if (t < 64) {   // wave 0: exclusive scan of degrees
        int carry = 0;
        #pragma unroll
        for (int c = 0; c < (NPB + 63) / 64; c++) {
            int idx = c * 64 + t;
            int hv = (idx < nn) ? h[idx] : 0;
            int s = hv;
            #pragma unroll
            for (int d2 = 1; d2 < 64; d2 <<= 1) {
                int u = __shfl_up(s, d2, 64);
                if (t >= d2) s += u;
            }
            if (idx < nn) {
                int ex = base_b + carry + (s - hv);
                pfx[idx] = ex;
                row_ptr[nb + idx] = ex;
                dinv[nb + idx] = rsqrtf((float)(hv + 1));   // +1 self-loop
            }
            carry += __shfl(s, 63, 64);
        }
    }
    __syncthreads();
    for (int i = t; i < nn; i += 512) h[i] = 0;   // reuse as fill counters
    __syncthreads();
    for (int i = t; i < n; i += 512) {            // scatter from LDS (no global re-read)
        int dl = ldst[i];
        int pos = pfx[dl] + atomicAdd(&h[dl], 1);
        col[pos] = lsrc[i];
    }
    if (b == 0 && t == 0) row_ptr[N_NODES] = N_EDGES;
}

// ---------------- k_agg1g2: Agg1 (+bias+ReLU, pre-scale) + MFMA GEMM2 -> H2s fp16 ----------------
// Block = 16 nodes, each wave serially aggregates 4 nodes with a full-row gather per
// edge (64 lanes x half2 = 256B). e0/e1 forced to SGPR via readfirstlane so col[e..]
// are SGPR scalar loads; dinv[col[e]] are uniform-address scalar loads (SMEM pipe)
// and the sym-norm scale folds into the accumulate. 8 gathers in flight (unroll-16
// measured neutral in round 10 — reverted).

__global__ __launch_bounds__(256) void k_agg1g2(const __half* __restrict__ H1s,
                                                const int* __restrict__ row_ptr,
                                                const int* __restrict__ col,
                                                const float* __restrict__ dinv,
                                                const float* __restrict__ b1,
                                                const __half* __restrict__ W2T,
                                                __half* __restrict__ H2s) {
    __shared__ __align__(16) _Float16 rows[16][136];   // +8 pad: 16B-aligned, 2-way-max banks
    const int wave = threadIdx.x >> 6;
    const int lane = threadIdx.x & 63;
    const __half2* base = (const __half2*)H1s;   // row stride 64 half2
    const float2 bb = ((const float2*)b1)[lane];
    const int d00 = blockIdx.x * 16 + wave * 4;

    #pragma unroll
    for (int i = 0; i < 4; i++) {
        const int d = d00 + i;
        const int e0 = __builtin_amdgcn_readfirstlane(row_ptr[d]);
        const int e1 = __builtin_amdgcn_readfirstlane(row_ptr[d + 1]);
        const float dd = dinv[d];
        float ax = 0.f, ay = 0.f;
        int e = e0;
        for (; e + 7 < e1; e += 8) {
            int s0 = col[e],     s1 = col[e + 1], s2 = col[e + 2], s3 = col[e + 3];
            int s4 = col[e + 4], s5 = col[e + 5], s6 = col[e + 6], s7 = col[e + 7];
            float d0 = dinv[s0], d1 = dinv[s1], d2 = dinv[s2], d3 = dinv[s3];
            float d4 = dinv[s4], d5 = dinv[s5], d6 = dinv[s6], d7 = dinv[s7];
            float2 f0 = __half22float2(base[(long)s0 * 64 + lane]);
            float2 f1 = __half22float2(base[(long)s1 * 64 + lane]);
            float2 f2 = __half22float2(base[(long)s2 * 64 + lane]);
            float2 f3 = __half22float2(base[(long)s3 * 64 + lane]);
            float2 f4 = __half22float2(base[(long)s4 * 64 + lane]);
            float2 f5 = __half22float2(base[(long)s5 * 64 + lane]);
            float2 f6 = __half22float2(base[(long)s6 * 64 + lane]);
            float2 f7 = __half22float2(base[(long)s7 * 64 + lane]);
            ax += d0 * f0.x + d1 * f1.x + d2 * f2.x + d3 * f3.x
                + d4 * f4.x + d5 * f5.x + d6 * f6.x + d7 * f7.x;
            ay += d0 * f0.y + d1 * f1.y + d2 * f2.y + d3 * f3.y
                + d4 * f4.y + d5 * f5.y + d6 * f6.y + d7 * f7.y;
        }
        for (; e + 3 < e1; e += 4) {
            int s0 = col[e], s1 = col[e + 1], s2 = col[e + 2], s3 = col[e + 3];
            float d0 = dinv[s0], d1 = dinv[s1], d2 = dinv[s2], d3 = dinv[s3];
            float2 f0 = __half22float2(base[(long)s0 * 64 + lane]);
            float2 f1 = __half22float2(base[(long)s1 * 64 + lane]);
            float2 f2 = __half22float2(base[(long)s2 * 64 + lane]);
            float2 f3 = __half22float2(base[(long)s3 * 64 + lane]);
            ax += d0 * f0.x + d1 * f1.x + d2 * f2.x + d3 * f3.x;
            ay += d0 * f0.y + d1 * f1.y + d2 * f2.y + d3 * f3.y;
        }
        for (; e < e1; e++) {
            int s = col[e];
            float dv = dinv[s];
            float2 f = __half22float2(base[(long)s * 64 + lane]);
            ax += dv * f.x; ay += dv * f.y;
        }
        // self-loop (unscaled H1 row x dd)
        float2 fs = __half22float2(base[(long)d * 64 + lane]);
        ax += dd * fs.x; ay += dd * fs.y;
        // bias + relu, then pre-scale by dd so the layer-2 MFMA needs no post-scale
        float ox = fmaxf(dd * ax + bb.x, 0.f) * dd;
        float oy = fmaxf(dd * ay + bb.y, 0.f) * dd;
        *(__half2*)&rows[wave * 4 + i][lane * 2] =
            __halves2half2(__float2half_rn(ox), __float2half_rn(oy));
    }
    __syncthreads();

    if (wave < 3) {   // 3 n-tiles of 16 cols (48 padded, 40 real)
        const int m16 = lane & 15;
        const int kq  = lane >> 4;
        floatx4 acc = (floatx4)0.f;
        #pragma unroll
        for (int ks = 0; ks < 4; ks++) {
            half8 a = *(const half8*)&rows[m16][ks * 32 + kq * 8];
            half8 b = *(const half8*)&W2T[(wave * 16 + m16) * HIDDEN + ks * 32 + kq * 8];
            acc = __builtin_amdgcn_mfma_f32_16x16x32_f16(a, b, acc, 0, 0, 0);
        }
        const int c = wave * 16 + m16;
        if (c < NCLS) {
            const int gr0 = blockIdx.x * 16 + kq * 4;
            #pragma unroll
            for (int r = 0; r < 4; r++)
                H2s[(long)(gr0 + r) * NCLS + c] = __float2half_rn(acc[r]);
        }
    }
}

// ---------------- Aggregation 2 (+bias) -> fp32 out. 12 nodes x 5 half8-lanes per wave ----------------

__global__ __launch_bounds__(256) void k_agg2(const __half* __restrict__ H2s,
                                              const int* __restrict__ row_ptr,
                                              const int* __restrict__ col,
                                              const float* __restrict__ dinv,
                                              const float* __restrict__ b2,
                                              float* __restrict__ out) {
    const int wave = threadIdx.x >> 6;
    const int lane = threadIdx.x & 63;
    const int g = lane / 5;               // 0..11 active, lanes 60-63 idle
    const int f = lane - g * 5;           // 0..4 -> feats 8f..8f+7
    const int d = blockIdx.x * 48 + wave * 12 + g;
    const bool act = (g < 12) && (d < N_NODES);
    int e0 = 0, e1 = 0;
    if (act) { e0 = row_ptr[d]; e1 = row_ptr[d + 1]; }
    const half8* base8 = (const half8*)H2s;   // row stride 5 half8
    float s0 = 0.f, s1 = 0.f, s2 = 0.f, s3 = 0.f, s4 = 0.f, s5 = 0.f, s6 = 0.f, s7 = 0.f;
    int e = e0;
    while (__any(e < e1)) {
        #pragma unroll
        for (int u = 0; u < 8; u++) {     // 8 gathers in flight per group
            if (e + u < e1) {
                half8 v = base8[(long)col[e + u] * 5 + f];
                s0 += (float)v[0]; s1 += (float)v[1]; s2 += (float)v[2]; s3 += (float)v[3];
                s4 += (float)v[4]; s5 += (float)v[5]; s6 += (float)v[6]; s7 += (float)v[7];
            }
        }
        e += 8;
    }
    if (act) {
        half8 v = base8[(long)d * 5 + f];   // self-loop (pre-scaled)
        s0 += (float)v[0]; s1 += (float)v[1]; s2 += (float)v[2]; s3 += (float)v[3];
        s4 += (float)v[4]; s5 += (float)v[5]; s6 += (float)v[6]; s7 += (float)v[7];
        float dd = dinv[d];
        float4 bb0 = ((const float4*)b2)[f * 2];
        float4 bb1 = ((const float4*)b2)[f * 2 + 1];
        float4 o0 = make_float4(dd * s0 + bb0.x, dd * s1 + bb0.y, dd * s2 + bb0.z, dd * s3 + bb0.w);
        float4 o1 = make_float4(dd * s4 + bb1.x, dd * s5 + bb1.y, dd * s6 + bb1.z, dd * s7 + bb1.w);
        ((float4*)out)[(long)d * 10 + f * 2]     = o0;
        ((float4*)out)[(long)d * 10 + f * 2 + 1] = o1;
    }
}

// ---------------- launch ----------------

extern "C" void kernel_launch(void* const* d_in, const int* in_sizes, int n_in,
                              void* d_out, int out_size, void* d_ws, size_t ws_size,
                              hipStream_t stream) {
    const float* x  = (const float*)d_in[0];
    const int*   ei = (const int*)d_in[1];
    const float* W1 = (const float*)d_in[2];
    const float* b1 = (const float*)d_in[3];
    const float* W2 = (const float*)d_in[4];
    const float* b2 = (const float*)d_in[5];
    const int* srcE = ei;
    const int* dstE = ei + N_EDGES;

    int*   row_ptr = (int*)d_ws;                    // 100032 ints
    int*   bfill   = row_ptr + 100032;              // 256
    int*   col     = bfill + 256;                   // 1600000
    float* dinv    = (float*)(col + N_EDGES);       // 100032 floats
    __half* H1s    = (__half*)(dinv + 100032);      // 12.8M halfs (25.6 MB)
    __half* H2s    = H1s + (long)N_NODES * HIDDEN;  // 4M halfs (8 MB)
    __half* W1T    = H2s + (long)N_NODES * NCLS;    // 32768 halfs
    __half* W2T    = W1T + IN_DIM * HIDDEN;         // 6144 halfs
    unsigned long long* bpair = (unsigned long long*)(W2T + NCLS_PAD * HIDDEN);  // 2.1M (16.8 MB)

    k_prep   <<<130, 256, 0, stream>>>(W1, W1T, W2, W2T, bfill);
    k_binmm  <<<BIN_BLOCKS + GEMM1_BLOCKS, 256, 0, stream>>>(srcE, dstE, bfill, bpair, x, W1T, H1s);
    k_build  <<<N_BUCKETS, 512, 0, stream>>>(bfill, bpair, row_ptr, dinv, col);
    k_agg1g2 <<<N_NODES / 16, 256, 0, stream>>>(H1s, row_ptr, col, dinv, b1, W2T, H2s);
    k_agg2   <<<(N_NODES + 47) / 48, 256, 0, stream>>>(H2s, row_ptr, col, dinv, b2, (float*)d_out);
}